// Round 8
// baseline (559.629 us; speedup 1.0000x reference)
//
#include <hip/hip_runtime.h>
#include <cstdint>

#define B_ 128
#define T_ 1024
#define D_ 256
#define U_ 48

// ---------------------------------------------------------------------------
// K1: logits[row][u] = sum_d x[row][d]*kernel[d][u] + bias[u].
// R7 accounting: every thread read ALL of K from LDS (3072 ds_read_b128),
// LDS-throughput-bound at ~60 us. R8: register-tiled 8 rows x 8 u per
// thread — each K chunk (8d x 8u, 16 b128) is loaded ONCE into registers and
// reused across 8 rows -> 512 b128/thread (6x fewer). 512 blocks x 192 thr
// (block covers 256 rows; us=tid>>5 picks u-octet, rg=tid&31 picks row-octet).
// Per-(row,u) accumulation order remains d-ascending -> bit-identical logits.
// ---------------------------------------------------------------------------
__global__ __launch_bounds__(192, 1) void k_logits(const float* __restrict__ x,
                                                   const float* __restrict__ kern,
                                                   const float* __restrict__ bias,
                                                   float* __restrict__ logits) {
    __shared__ float K[D_ * U_];   // 48 KB
    __shared__ float bsh[U_];
    const int tid = threadIdx.x;
    for (int i = tid; i < D_ * U_; i += 192) K[i] = kern[i];
    if (tid < U_) bsh[tid] = bias[tid];
    __syncthreads();

    const int rg = tid & 31;              // row-octet 0..31
    const int us = tid >> 5;              // u-octet  0..5
    const int u0 = us * 8;
    const long row0 = (long)blockIdx.x * 256 + (long)rg * 8;
    const float* xbase = x + row0 * D_;

    float acc[8][8];
#pragma unroll
    for (int r = 0; r < 8; ++r)
#pragma unroll
        for (int j = 0; j < 8; ++j) acc[r][j] = 0.0f;

#pragma unroll 1
    for (int c = 0; c < D_ / 8; ++c) {    // 32 chunks of 8 d-values
        float4 k0[8], k1[8];
#pragma unroll
        for (int dd = 0; dd < 8; ++dd) {
            const float4* kp = (const float4*)&K[(c * 8 + dd) * U_ + u0];
            k0[dd] = kp[0];
            k1[dd] = kp[1];
        }
#pragma unroll
        for (int r = 0; r < 8; ++r) {
            const float4* xp = (const float4*)(xbase + (long)r * D_ + c * 8);
            const float4 xa = xp[0];
            const float4 xb = xp[1];
            const float xs[8] = {xa.x, xa.y, xa.z, xa.w, xb.x, xb.y, xb.z, xb.w};
#pragma unroll
            for (int dd = 0; dd < 8; ++dd) {     // d ascending within chunk
                acc[r][0] += xs[dd] * k0[dd].x;
                acc[r][1] += xs[dd] * k0[dd].y;
                acc[r][2] += xs[dd] * k0[dd].z;
                acc[r][3] += xs[dd] * k0[dd].w;
                acc[r][4] += xs[dd] * k1[dd].x;
                acc[r][5] += xs[dd] * k1[dd].y;
                acc[r][6] += xs[dd] * k1[dd].z;
                acc[r][7] += xs[dd] * k1[dd].w;
            }
        }
    }

#pragma unroll
    for (int r = 0; r < 8; ++r) {
        float4 v0, v1;
        v0.x = acc[r][0] + bsh[u0 + 0];
        v0.y = acc[r][1] + bsh[u0 + 1];
        v0.z = acc[r][2] + bsh[u0 + 2];
        v0.w = acc[r][3] + bsh[u0 + 3];
        v1.x = acc[r][4] + bsh[u0 + 4];
        v1.y = acc[r][5] + bsh[u0 + 5];
        v1.z = acc[r][6] + bsh[u0 + 6];
        v1.w = acc[r][7] + bsh[u0 + 7];
        float4* op = (float4*)(logits + (row0 + r) * U_ + u0);
        op[0] = v0;
        op[1] = v1;
    }
}

// Max-plus body: m = max_v(state[v] + tc[v]); LDS float4 view, float2-paired
// adds. (R6-verified structure.)
__device__ __forceinline__ float step_max_lds(const float4* sb, const float2* tc2) {
    float n0 = -3.0e38f, n1 = -3.0e38f, n2 = -3.0e38f, n3 = -3.0e38f;
#pragma unroll
    for (int k = 0; k < U_ / 4; k += 4) {
        float4 s0 = sb[k + 0];
        float4 s1 = sb[k + 1];
        float4 s2 = sb[k + 2];
        float4 s3 = sb[k + 3];
        float2 p0 = make_float2(s0.x + tc2[2*k+0].x, s0.y + tc2[2*k+0].y);
        float2 p1 = make_float2(s0.z + tc2[2*k+1].x, s0.w + tc2[2*k+1].y);
        float2 p2 = make_float2(s1.x + tc2[2*k+2].x, s1.y + tc2[2*k+2].y);
        float2 p3 = make_float2(s1.z + tc2[2*k+3].x, s1.w + tc2[2*k+3].y);
        float2 p4 = make_float2(s2.x + tc2[2*k+4].x, s2.y + tc2[2*k+4].y);
        float2 p5 = make_float2(s2.z + tc2[2*k+5].x, s2.w + tc2[2*k+5].y);
        float2 p6 = make_float2(s3.x + tc2[2*k+6].x, s3.y + tc2[2*k+6].y);
        float2 p7 = make_float2(s3.z + tc2[2*k+7].x, s3.w + tc2[2*k+7].y);
        n0 = fmaxf(n0, fmaxf(fmaxf(p0.x, p0.y), fmaxf(p1.x, p1.y)));
        n1 = fmaxf(n1, fmaxf(fmaxf(p2.x, p2.y), fmaxf(p3.x, p3.y)));
        n2 = fmaxf(n2, fmaxf(fmaxf(p4.x, p4.y), fmaxf(p5.x, p5.y)));
        n3 = fmaxf(n3, fmaxf(fmaxf(p6.x, p6.y), fmaxf(p7.x, p7.y)));
    }
    return fmaxf(fmaxf(n0, n1), fmaxf(n2, n3));
}

// ---------------------------------------------------------------------------
// K2: Viterbi forward (LDS broadcast + guard-free grouped loop, R6-verified).
// ---------------------------------------------------------------------------
__global__ __launch_bounds__(64, 1) void k_forward(const float* __restrict__ trans,
                                                   const float* __restrict__ logits,
                                                   float* __restrict__ delta) {
    __shared__ float4 sbuf[2][U_ / 4];    // parity double buffer, 2x48 floats
    const int lane = threadIdx.x;
    const int b = blockIdx.x;
    const int u = (lane < U_) ? lane : (U_ - 1);

    float2 tc2[U_ / 2];
#pragma unroll
    for (int v = 0; v < U_; v += 2) {
        tc2[v / 2].x = trans[v * U_ + u];
        tc2[v / 2].y = trans[(v + 1) * U_ + u];
    }

    const float* lin = logits + (long)b * T_ * U_;
    float* dout = delta + (long)b * T_ * U_;

    float state = lin[u];                 // delta_0 = logits row 0
    dout[u] = state;                      // dup-writes (lanes 48-63) benign
    ((float*)sbuf[0])[u] = state;         // t=0 parity 0

    float pf[8];
#pragma unroll
    for (int i = 0; i < 8; ++i) pf[i] = lin[(1 + i) * U_ + u];  // rows 1..8

    const float* lp = lin + 9 * U_ + u;   // prefetch base: row tb+8 for tb=1
    float* dp = dout + 1 * U_ + u;        // store base: row tb

#pragma unroll 1
    for (int g = 0; g < 127; ++g) {       // t = 1+8g .. 8+8g  (1..1016)
#pragma unroll
        for (int j = 0; j < 8; ++j) {
            const float logit = pf[j];
            pf[j] = lp[j * U_];                       // imm offset j*192 B

            const float4* sb = sbuf[j & 1];           // parity (t-1)&1 == j&1
            const float m = step_max_lds(sb, tc2);
            state = logit + m;                        // exact ref op order
            ((float*)sbuf[(j & 1) ^ 1])[u] = state;
            dp[j * U_] = state;                       // imm offset j*192 B
        }
        lp += 8 * U_;
        dp += 8 * U_;
    }

    // tail: t = 1017..1023 (7 steps); pf[0..6] hold rows 1017..1023
#pragma unroll
    for (int j = 0; j < 7; ++j) {
        const float logit = pf[j];
        const float4* sb = sbuf[j & 1];               // (t-1)=1016+j parity j&1
        const float m = step_max_lds(sb, tc2);
        state = logit + m;
        ((float*)sbuf[(j & 1) ^ 1])[u] = state;
        dp[j * U_] = state;
    }
}

// Fallback (in-place) variant if ws can't fit a second delta buffer.
__global__ __launch_bounds__(64, 1) void k_forward_inplace(const float* __restrict__ trans,
                                                           float* __restrict__ delta) {
    __shared__ float4 sbuf[2][U_ / 4];
    const int lane = threadIdx.x;
    const int b = blockIdx.x;
    const int u = (lane < U_) ? lane : (U_ - 1);

    float2 tc2[U_ / 2];
#pragma unroll
    for (int v = 0; v < U_; v += 2) {
        tc2[v / 2].x = trans[v * U_ + u];
        tc2[v / 2].y = trans[(v + 1) * U_ + u];
    }

    float* base = delta + (long)b * T_ * U_;
    float state = base[u];
    ((float*)sbuf[0])[u] = state;

#pragma unroll 1
    for (int t = 1; t < T_; ++t) {
        const float logit = base[(long)t * U_ + u];
        const float m = step_max_lds(sbuf[(t - 1) & 1], tc2);
        state = logit + m;
        ((float*)sbuf[t & 1])[u] = state;
        base[(long)t * U_ + u] = state;
    }
}

// ---------------------------------------------------------------------------
// K3: backpointers, LDS-broadcast pattern (R7-verified). 32 contiguous rows
// per block; strict-> ascending scan == numpy first-index tie-break;
// candidates bit-identical to K2's.
// ---------------------------------------------------------------------------
#define BP_ROWS 32
__global__ __launch_bounds__(64, 1) void k_bp(const float* __restrict__ trans,
                                              const float* __restrict__ delta,
                                              unsigned char* __restrict__ bp) {
    __shared__ float sbuf[2][U_];         // row parity double buffer
    const int lane = threadIdx.x;
    const int u = (lane < U_) ? lane : (U_ - 1);

    float tc[U_];
#pragma unroll
    for (int v = 0; v < U_; ++v) tc[v] = trans[v * U_ + u];

    const int NROW = B_ * (T_ - 1);       // 130944
    const int row0 = blockIdx.x * BP_ROWS;
    if (row0 >= NROW) return;

    int b = row0 / (T_ - 1);              // uniform, once per block
    int tm1 = row0 - b * (T_ - 1);        // (t-1) in 0..1022

    float dval = delta[((long)b * T_ + tm1) * U_ + u];   // prefetch row0

#pragma unroll 1
    for (int i = 0; i < BP_ROWS; ++i) {
        const int row = row0 + i;
        if (row >= NROW) break;           // uniform guard

        sbuf[i & 1][u] = dval;            // stage current row (dup benign)

        // advance cursor, prefetch next row
        int bn = b, tn = tm1 + 1;
        if (tn == T_ - 1) { tn = 0; bn = b + 1; }
        float dnext = 0.0f;
        if (row + 1 < NROW) dnext = delta[((long)bn * T_ + tn) * U_ + u];

        const float4* sb4 = (const float4*)sbuf[i & 1];
        float best = -3.4e38f;
        int bi = 0;
#pragma unroll
        for (int k = 0; k < U_ / 4; ++k) {
            float4 s = sb4[k];            // uniform broadcast read
            float c0 = s.x + tc[4*k+0];
            float c1 = s.y + tc[4*k+1];
            float c2 = s.z + tc[4*k+2];
            float c3 = s.w + tc[4*k+3];
            bi = (c0 > best) ? 4*k+0 : bi;  best = fmaxf(best, c0);
            bi = (c1 > best) ? 4*k+1 : bi;  best = fmaxf(best, c1);
            bi = (c2 > best) ? 4*k+2 : bi;  best = fmaxf(best, c2);
            bi = (c3 > best) ? 4*k+3 : bi;  best = fmaxf(best, c3);
        }
        bp[(long)row * U_ + u] = (unsigned char)bi;   // dup-writes benign

        b = bn; tm1 = tn; dval = dnext;
    }
}

// ---------------------------------------------------------------------------
// K4: backtrace, R8 parallel-segment rewrite. The R0-R7 version was a
// lane-0 serial chase: 1023 dependent ds_read_u8 (~60+ us). Now:
//  - bpl padded with an identity row at k=1023 (so every lane runs a
//    uniform 16-step segment; virtual tag_1024 == tag_1023 == argmax).
//  - Phase A: lane i composes its segment map for ALL 48 entries
//    (16 steps x 48 independent pipelined ds_read_u8).
//  - Phase B: lane 0 chains the 64 segment maps (64 dependent reads).
//  - Phase C: lane i re-chases its 16 steps from the known boundary tag,
//    writing tags[k]. All-integer -> exact.
// ---------------------------------------------------------------------------
__global__ __launch_bounds__(64, 1) void k_back(const float* __restrict__ delta,
                                                const unsigned char* __restrict__ bp,
                                                float* __restrict__ out) {
    __shared__ unsigned char bpl[T_ * U_];        // 49152 B (row 1023 = identity)
    __shared__ unsigned char maps[64][U_];        // 3072 B
    __shared__ float tags[T_];                    // 4096 B
    __shared__ float fin[U_];
    __shared__ unsigned char bt[65];
    const int lane = threadIdx.x;
    const int b = blockIdx.x;

    // stage bp[b] (49104 B = 3069 uint4), vectorized
    const uint4* src = (const uint4*)(bp + (long)b * (T_ - 1) * U_);
    uint4* dst = (uint4*)bpl;
#pragma unroll 1
    for (int i = lane; i < (T_ - 1) * U_ / 16; i += 64) dst[i] = src[i];
    if (lane < U_) bpl[(T_ - 1) * U_ + lane] = (unsigned char)lane;  // identity row
    if (lane < U_) fin[lane] = delta[((long)b * T_ + (T_ - 1)) * U_ + lane];
    __syncthreads();

    // Phase A: segment map for all 48 entries. Segment i covers k=16i..16i+15.
    int cur[U_];
#pragma unroll
    for (int e = 0; e < U_; ++e) cur[e] = e;
    const int klo = lane * 16;
#pragma unroll 1
    for (int s = 15; s >= 0; --s) {
        const unsigned char* rowp = &bpl[(klo + s) * U_];
#pragma unroll
        for (int e = 0; e < U_; ++e) cur[e] = rowp[cur[e]];
    }
#pragma unroll
    for (int e = 0; e < U_; ++e) maps[lane][e] = (unsigned char)cur[e];
    __syncthreads();

    // Phase B: final argmax (strict >, ascending = numpy first-index), then
    // chain the 64 segment maps. bt[i] = tag at index 16*i; bt[64] = tag_1023.
    if (lane == 0) {
        float best = fin[0];
        int tag = 0;
        for (int uu = 1; uu < U_; ++uu)
            if (fin[uu] > best) { best = fin[uu]; tag = uu; }
        bt[64] = (unsigned char)tag;
        for (int i = 63; i >= 0; --i) {
            tag = maps[i][tag];
            bt[i] = (unsigned char)tag;
        }
    }
    __syncthreads();

    // Phase C: re-chase segment from known entry, writing tags[k].
    int e = bt[lane + 1];
#pragma unroll 1
    for (int s = 15; s >= 0; --s) {
        e = bpl[(klo + s) * U_ + e];
        tags[klo + s] = (float)e;
    }
    __syncthreads();

    float* o = out + (long)b * T_;
    for (int i = lane; i < T_; i += 64) o[i] = tags[i];
}

// ---------------------------------------------------------------------------
extern "C" void kernel_launch(void* const* d_in, const int* in_sizes, int n_in,
                              void* d_out, int out_size, void* d_ws, size_t ws_size,
                              hipStream_t stream) {
    const float* x     = (const float*)d_in[0];   // (B,T,D)
    const float* kern  = (const float*)d_in[1];   // (D,U)
    const float* bias  = (const float*)d_in[2];   // (U,)
    const float* trans = (const float*)d_in[3];   // (U,U)
    float* out = (float*)d_out;                   // (B,T) fp32 tags

    const size_t NBT = (size_t)B_ * T_ * U_ * sizeof(float);  // 25,165,824 B

    float* logits = (float*)d_ws;
    const bool two_buf = ws_size >= 2 * NBT + (size_t)B_ * T_ * U_;
    float* delta = two_buf ? (float*)((char*)d_ws + NBT) : logits;
    unsigned char* bp = (unsigned char*)d_ws + (two_buf ? 2 * NBT : NBT);

    const int NROW = B_ * (T_ - 1);
    const int bp_grid = (NROW + BP_ROWS - 1) / BP_ROWS;   // 4092

    k_logits<<<512, 192, 0, stream>>>(x, kern, bias, logits);
    if (two_buf)
        k_forward<<<B_, 64, 0, stream>>>(trans, logits, delta);
    else
        k_forward_inplace<<<B_, 64, 0, stream>>>(trans, logits);
    k_bp  <<<bp_grid, 64, 0, stream>>>(trans, delta, bp);
    k_back<<<B_,      64, 0, stream>>>(delta, bp, out);
}